// Round 1
// baseline (50.617 us; speedup 1.0000x reference)
//
#include <hip/hip_runtime.h>

#define NEG_SLOPE 0.01f

__device__ __forceinline__ float leaky(float v) {
    return v > 0.0f ? v : NEG_SLOPE * v;
}

// ---------------- Kernel 1: node MLP ----------------
// One wave (64 lanes) per row (b,n); 4 rows per 256-thread block.
// h1[k] per lane -> LDS; h2[k] = sum_c h1[c]*Wn2[c][k]; node_out = sum_k h2[k]*Wn3[k] + bn3.
__global__ __launch_bounds__(256) void k1_node(
    const float* __restrict__ x,
    const float* __restrict__ Wn1, const float* __restrict__ bn1,
    const float* __restrict__ Wn2, const float* __restrict__ bn2,
    const float* __restrict__ Wn3, const float* __restrict__ bn3,
    float* __restrict__ node_out)
{
    __shared__ float sh[4][64];
    const int lane = threadIdx.x & 63;
    const int wv   = threadIdx.x >> 6;
    const int row  = blockIdx.x * 4 + wv;   // b*N + n

    const float x0 = x[row * 2 + 0];
    const float x1 = x[row * 2 + 1];

    // h1 = leaky(x @ Wn1 + bn1)   (Wn1 is (2,64) row-major)
    const float h = leaky(fmaf(x0, Wn1[lane], fmaf(x1, Wn1[64 + lane], bn1[lane])));
    sh[wv][lane] = h;
    __syncthreads();

    // h2 = leaky(h1 @ Wn2 + bn2)  (Wn2 is (64,64) row-major; lane owns column k=lane)
    float acc = bn2[lane];
    #pragma unroll
    for (int c = 0; c < 64; ++c)
        acc = fmaf(sh[wv][c], Wn2[c * 64 + lane], acc);
    const float h2 = leaky(acc);

    // node_out = h2 @ Wn3 + bn3  (Wn3 is (64,1))
    float p = h2 * Wn3[lane];
    #pragma unroll
    for (int off = 32; off > 0; off >>= 1)
        p += __shfl_xor(p, off, 64);
    if (lane == 0)
        node_out[row] = p + bn3[0];
}

// ---------------- Kernel 2: pairwise coupling ----------------
// One block per (b,i). 256 threads; thread t handles j = t and j = t+256.
// h1 = leaky(pj[b,j] + pi[b,i] + bc1); h2 = leaky(h1 @ Wc2 + bc2);
// cout = h2 @ Wc3 + bc3; acc += sigmoid(A_param[i,j] - diag) * cout.
__global__ __launch_bounds__(256) void k2_pair(
    const float* __restrict__ x,
    const float* __restrict__ node_out,
    const float* __restrict__ Wc1, const float* __restrict__ bc1,
    const float* __restrict__ Wc2, const float* __restrict__ bc2,
    const float* __restrict__ Wc3, const float* __restrict__ bc3,
    const float* __restrict__ A_param,
    float* __restrict__ out)
{
    __shared__ float sW2[256];
    __shared__ float sB2[16];
    __shared__ float sW3[16];
    __shared__ float sred[4];

    const int t  = threadIdx.x;
    const int bi = blockIdx.x;          // b*512 + i
    const int b  = bi >> 9;
    const int i  = bi & 511;

    sW2[t] = Wc2[t];
    if (t < 16) { sB2[t] = bc2[t]; sW3[t] = Wc3[t]; }

    // uniform per block: pi[b,i] + bc1  (Wc1 is (4,16) row-major; rows 2..3 are Wc1_i)
    const float xi0 = x[bi * 2 + 0];
    const float xi1 = x[bi * 2 + 1];
    float piu[16];
    #pragma unroll
    for (int c = 0; c < 16; ++c)
        piu[c] = fmaf(xi0, Wc1[32 + c], fmaf(xi1, Wc1[48 + c], bc1[c]));

    __syncthreads();

    const float b3 = bc3[0];

    // pj for j0 = t, j1 = t+256 (rows 0..1 of Wc1 are Wc1_j), then h1 = leaky(pj + piu)
    float h1a[16], h1b[16];
    {
        const int j0 = t, j1 = t + 256;
        const float xa0 = x[(b * 512 + j0) * 2 + 0];
        const float xa1 = x[(b * 512 + j0) * 2 + 1];
        const float xb0 = x[(b * 512 + j1) * 2 + 0];
        const float xb1 = x[(b * 512 + j1) * 2 + 1];
        #pragma unroll
        for (int c = 0; c < 16; ++c) {
            h1a[c] = leaky(piu[c] + fmaf(xa0, Wc1[c], xa1 * Wc1[16 + c]));
            h1b[c] = leaky(piu[c] + fmaf(xb0, Wc1[c], xb1 * Wc1[16 + c]));
        }
    }

    // h2 = h1 @ Wc2 + bc2, both j's share each Wc2 element (LDS broadcast float4)
    float h2a[16], h2b[16];
    #pragma unroll
    for (int k = 0; k < 16; ++k) { h2a[k] = sB2[k]; h2b[k] = sB2[k]; }

    const float4* sW24 = (const float4*)sW2;
    #pragma unroll
    for (int c = 0; c < 16; ++c) {
        #pragma unroll
        for (int q = 0; q < 4; ++q) {
            const float4 w = sW24[c * 4 + q];
            h2a[q*4+0] = fmaf(h1a[c], w.x, h2a[q*4+0]);
            h2a[q*4+1] = fmaf(h1a[c], w.y, h2a[q*4+1]);
            h2a[q*4+2] = fmaf(h1a[c], w.z, h2a[q*4+2]);
            h2a[q*4+3] = fmaf(h1a[c], w.w, h2a[q*4+3]);
            h2b[q*4+0] = fmaf(h1b[c], w.x, h2b[q*4+0]);
            h2b[q*4+1] = fmaf(h1b[c], w.y, h2b[q*4+1]);
            h2b[q*4+2] = fmaf(h1b[c], w.z, h2b[q*4+2]);
            h2b[q*4+3] = fmaf(h1b[c], w.w, h2b[q*4+3]);
        }
    }

    // cout = leaky(h2) @ Wc3 + bc3
    float ca = b3, cb = b3;
    #pragma unroll
    for (int k = 0; k < 16; ++k) {
        ca = fmaf(leaky(h2a[k]), sW3[k], ca);
        cb = fmaf(leaky(h2b[k]), sW3[k], cb);
    }

    // A[i,j] = sigmoid(A_param[i,j] - (i==j)*1e5)
    const float za = A_param[i * 512 + t]       - (i == t       ? 1e5f : 0.0f);
    const float zb = A_param[i * 512 + t + 256] - (i == t + 256 ? 1e5f : 0.0f);
    const float Aa = 1.0f / (1.0f + __expf(-za));
    const float Ab = 1.0f / (1.0f + __expf(-zb));

    float acc = fmaf(Aa, ca, Ab * cb);

    // block reduction: butterfly within wave, then across 4 waves via LDS
    #pragma unroll
    for (int off = 32; off > 0; off >>= 1)
        acc += __shfl_xor(acc, off, 64);
    const int wv = t >> 6, lane = t & 63;
    if (lane == 0) sred[wv] = acc;
    __syncthreads();
    if (t == 0) {
        const float s = sred[0] + sred[1] + sred[2] + sred[3];
        out[bi * 2 + 0] = x[bi * 2 + 1];          // out0 = x[...,1]
        out[bi * 2 + 1] = node_out[bi] + s;       // out1 = node_out + coupling
    }
}

extern "C" void kernel_launch(void* const* d_in, const int* in_sizes, int n_in,
                              void* d_out, int out_size, void* d_ws, size_t ws_size,
                              hipStream_t stream) {
    const float* x       = (const float*)d_in[0];
    const float* Wn1     = (const float*)d_in[1];
    const float* bn1     = (const float*)d_in[2];
    const float* Wn2     = (const float*)d_in[3];
    const float* bn2     = (const float*)d_in[4];
    const float* Wn3     = (const float*)d_in[5];
    const float* bn3     = (const float*)d_in[6];
    const float* Wc1     = (const float*)d_in[7];
    const float* bc1     = (const float*)d_in[8];
    const float* Wc2     = (const float*)d_in[9];
    const float* bc2     = (const float*)d_in[10];
    const float* Wc3     = (const float*)d_in[11];
    const float* bc3     = (const float*)d_in[12];
    const float* A_param = (const float*)d_in[13];
    float* out = (float*)d_out;

    float* node_out = (float*)d_ws;   // B*N = 8192 floats

    const int BN = 16 * 512;          // 8192 rows

    k1_node<<<BN / 4, 256, 0, stream>>>(x, Wn1, bn1, Wn2, bn2, Wn3, bn3, node_out);
    k2_pair<<<BN, 256, 0, stream>>>(x, node_out, Wc1, bc1, Wc2, bc2, Wc3, bc3,
                                    A_param, out);
}

// Round 3
// 40.303 us; speedup vs baseline: 1.2559x; 1.2559x over previous
//
#include <hip/hip_runtime.h>

#define NEG_SLOPE 0.01f

typedef _Float16 f16x4 __attribute__((ext_vector_type(4)));
typedef float    f32x4 __attribute__((ext_vector_type(4)));

__device__ __forceinline__ float leaky(float v) {
    // 0 < slope < 1  =>  leaky(v) == max(v, slope*v)
    return fmaxf(v, NEG_SLOPE * v);
}

// ---------------- Kernel 1: node MLP ----------------
// One wave (64 lanes) per row (b,n); 4 rows per 256-thread block.
__global__ __launch_bounds__(256) void k1_node(
    const float* __restrict__ x,
    const float* __restrict__ Wn1, const float* __restrict__ bn1,
    const float* __restrict__ Wn2, const float* __restrict__ bn2,
    const float* __restrict__ Wn3, const float* __restrict__ bn3,
    float* __restrict__ node_out)
{
    __shared__ float sh[4][64];
    const int lane = threadIdx.x & 63;
    const int wv   = threadIdx.x >> 6;
    const int row  = blockIdx.x * 4 + wv;   // b*N + n

    const float x0 = x[row * 2 + 0];
    const float x1 = x[row * 2 + 1];

    const float h = leaky(fmaf(x0, Wn1[lane], fmaf(x1, Wn1[64 + lane], bn1[lane])));
    sh[wv][lane] = h;
    __syncthreads();

    float acc = bn2[lane];
    #pragma unroll
    for (int c = 0; c < 64; ++c)
        acc = fmaf(sh[wv][c], Wn2[c * 64 + lane], acc);
    const float h2 = leaky(acc);

    float p = h2 * Wn3[lane];
    #pragma unroll
    for (int off = 32; off > 0; off >>= 1)
        p += __shfl_xor(p, off, 64);
    if (lane == 0)
        node_out[row] = p + bn3[0];
}

// ---------------- Kernel 2: pairwise coupling via MFMA ----------------
// One wave per (b,i). Tile = 16 j's. Per tile:
//   B1 = h1^T (lane: pair p=l&15, channels c4..c4+3), built from x on the fly
//   D1 = (Wc2^T)hi/lo x B1 + bc2      -> h2^T     (2 chained MFMAs)
//   B2 = leaky(D1) (same lane layout!) -> D2 = Wc3(bcast rows) x B2 + bc3 = cout
//   acc += sigmoid(A[i][j]) * cout[j]  (lanes 4-way duplicated; fix with x0.25)
__global__ __launch_bounds__(64) void k2_pair_mfma(
    const float* __restrict__ x,
    const float* __restrict__ node_out,
    const float* __restrict__ Wc1, const float* __restrict__ bc1,
    const float* __restrict__ Wc2, const float* __restrict__ bc2,
    const float* __restrict__ Wc3, const float* __restrict__ bc3,
    const float* __restrict__ A_param,
    float* __restrict__ out)
{
    const int l  = threadIdx.x;       // 0..63
    const int p  = l & 15;            // pair slot within tile
    const int c4 = (l >> 4) << 2;     // channel base
    const int bi = blockIdx.x;        // b*512 + i
    const int b  = bi >> 9;
    const int i  = bi & 511;

    // --- static fragments (hi/lo split so weight quantization error ~2^-22) ---
    // A1 = Wc2^T: lane l holds A1[row=p][k=c4+e] = Wc2[c4+e][p]
    // A2 = Wc3 broadcast rows: lane l holds Wc3[c4+e]
    f16x4 w2hi, w2lo, w3hi, w3lo;
    f32x4 c1;                          // C for MFMA1: bc2[c4+e] (D1 row = c4+reg)
    #pragma unroll
    for (int e = 0; e < 4; ++e) {
        const int c = c4 + e;
        const float w2 = Wc2[c * 16 + p];
        const _Float16 h2w = (_Float16)w2;
        w2hi[e] = h2w; w2lo[e] = (_Float16)(w2 - (float)h2w);
        const float w3 = Wc3[c];
        const _Float16 h3w = (_Float16)w3;
        w3hi[e] = h3w; w3lo[e] = (_Float16)(w3 - (float)h3w);
        c1[e] = bc2[c];
    }
    const float b3 = bc3[0];
    const f32x4 c2 = {b3, b3, b3, b3}; // C for MFMA2 (all rows identical)

    // pi[i][c] + bc1 (uniform over tiles), and Wc1_j columns for this lane
    const float xi0 = x[bi * 2 + 0];
    const float xi1 = x[bi * 2 + 1];
    float piu[4], wj0[4], wj1[4];
    #pragma unroll
    for (int e = 0; e < 4; ++e) {
        const int c = c4 + e;
        piu[e] = fmaf(xi0, Wc1[32 + c], fmaf(xi1, Wc1[48 + c], bc1[c]));
        wj0[e] = Wc1[c];
        wj1[e] = Wc1[16 + c];
    }

    const float* xb = x + b * 1024;       // x[b][j][2]
    const float* Ar = A_param + i * 512;  // A_param[i][*]

    float acc = 0.0f;
    #pragma unroll 4
    for (int t = 0; t < 32; ++t) {
        const int j = t * 16 + p;
        const float xj0 = xb[j * 2 + 0];
        const float xj1 = xb[j * 2 + 1];

        // h1[p][c4+e] = leaky(pj + pi + bc1)
        f16x4 b1;
        #pragma unroll
        for (int e = 0; e < 4; ++e)
            b1[e] = (_Float16)leaky(fmaf(xj0, wj0[e], fmaf(xj1, wj1[e], piu[e])));

        f32x4 d1 = __builtin_amdgcn_mfma_f32_16x16x16f16(w2lo, b1, c1, 0, 0, 0);
        d1 = __builtin_amdgcn_mfma_f32_16x16x16f16(w2hi, b1, d1, 0, 0, 0);

        // leaky(h2) -> B2 (already in B-operand layout)
        f16x4 b2;
        #pragma unroll
        for (int e = 0; e < 4; ++e)
            b2[e] = (_Float16)leaky(d1[e]);

        f32x4 d2 = __builtin_amdgcn_mfma_f32_16x16x16f16(w3lo, b2, c2, 0, 0, 0);
        d2 = __builtin_amdgcn_mfma_f32_16x16x16f16(w3hi, b2, d2, 0, 0, 0);
        // d2[0] = cout for pair j (all rows identical)

        const float z = Ar[j];
        float sig = __fdividef(1.0f, 1.0f + __expf(-z));
        if (j == i) sig = 0.0f;             // sigmoid(0 - 1e5) == 0 in f32
        acc = fmaf(sig, d2[0], acc);
    }

    // each j is covered by exactly 4 lanes with identical contributions
    #pragma unroll
    for (int off = 32; off > 0; off >>= 1)
        acc += __shfl_xor(acc, off, 64);

    if (l == 0) {
        out[bi * 2 + 0] = x[bi * 2 + 1];                 // out0 = x[...,1]
        out[bi * 2 + 1] = node_out[bi] + 0.25f * acc;    // out1
    }
}

extern "C" void kernel_launch(void* const* d_in, const int* in_sizes, int n_in,
                              void* d_out, int out_size, void* d_ws, size_t ws_size,
                              hipStream_t stream) {
    const float* x       = (const float*)d_in[0];
    const float* Wn1     = (const float*)d_in[1];
    const float* bn1     = (const float*)d_in[2];
    const float* Wn2     = (const float*)d_in[3];
    const float* bn2     = (const float*)d_in[4];
    const float* Wn3     = (const float*)d_in[5];
    const float* bn3     = (const float*)d_in[6];
    const float* Wc1     = (const float*)d_in[7];
    const float* bc1     = (const float*)d_in[8];
    const float* Wc2     = (const float*)d_in[9];
    const float* bc2     = (const float*)d_in[10];
    const float* Wc3     = (const float*)d_in[11];
    const float* bc3     = (const float*)d_in[12];
    const float* A_param = (const float*)d_in[13];
    float* out = (float*)d_out;

    float* node_out = (float*)d_ws;   // B*N = 8192 floats

    const int BN = 16 * 512;          // 8192 rows

    k1_node<<<BN / 4, 256, 0, stream>>>(x, Wn1, bn1, Wn2, bn2, Wn3, bn3, node_out);
    k2_pair_mfma<<<BN, 64, 0, stream>>>(x, node_out, Wc1, bc1, Wc2, bc2, Wc3, bc3,
                                        A_param, out);
}

// Round 4
// 33.025 us; speedup vs baseline: 1.5327x; 1.2204x over previous
//
#include <hip/hip_runtime.h>

#define NEG_SLOPE 0.01f

typedef _Float16 f16x4 __attribute__((ext_vector_type(4)));
typedef float    f32x4 __attribute__((ext_vector_type(4)));

__device__ __forceinline__ float leaky(float v) {
    // 0 < slope < 1  =>  leaky(v) == max(v, slope*v)
    return fmaxf(v, NEG_SLOPE * v);
}

// ws layout (floats):
//   [0,      8192)    node_out                (B*N)
//   [8192,   139264)  pj   (8192 rows x 16)   x@Wc1_j
//   [139264, 270336)  piu  (8192 rows x 16)   x@Wc1_i + bc1
//   [270336, 532480)  S    (512 x 512)        sigmoid(A_param), diag=0
#define WS_PJ   8192
#define WS_PIU  139264
#define WS_S    270336

// ---------------- Kernel 1: node MLP + precompute ----------------
// One wave per row (b,n); 4 rows per 256-thread block (2048 blocks).
// Also: threads of blocks 0..1023 compute one sigmoid(A) element each;
// lanes<16 write pj/piu rows; lane 0 writes node_out and out0.
__global__ __launch_bounds__(256) void k1_fused(
    const float* __restrict__ x,
    const float* __restrict__ Wn1, const float* __restrict__ bn1,
    const float* __restrict__ Wn2, const float* __restrict__ bn2,
    const float* __restrict__ Wn3, const float* __restrict__ bn3,
    const float* __restrict__ Wc1, const float* __restrict__ bc1,
    const float* __restrict__ A_param,
    float* __restrict__ ws, float* __restrict__ out)
{
    __shared__ float sh[4][64];
    const int t    = threadIdx.x;
    const int lane = t & 63;
    const int wv   = t >> 6;
    const int row  = blockIdx.x * 4 + wv;   // b*N + n

    const float x0 = x[row * 2 + 0];
    const float x1 = x[row * 2 + 1];

    // node layer 1
    const float h = leaky(fmaf(x0, Wn1[lane], fmaf(x1, Wn1[64 + lane], bn1[lane])));
    sh[wv][lane] = h;
    __syncthreads();

    // fused: sigmoid(A_param) table, diag zeroed (blocks 0..1023 cover 512*512)
    {
        const int g = blockIdx.x * 256 + t;
        if (g < 512 * 512) {
            const int i = g >> 9, j = g & 511;
            const float a = A_param[g];
            float s = __fdividef(1.0f, 1.0f + __expf(-a));
            if (i == j) s = 0.0f;
            ws[WS_S + g] = s;
        }
    }

    // fused: pj / piu rows for the coupling MLP
    if (lane < 16) {
        const float pj = fmaf(x0, Wc1[lane], x1 * Wc1[16 + lane]);
        const float pi = fmaf(x0, Wc1[32 + lane], fmaf(x1, Wc1[48 + lane], bc1[lane]));
        ws[WS_PJ  + row * 16 + lane] = pj;
        ws[WS_PIU + row * 16 + lane] = pi;
    }

    // node layer 2
    float acc = bn2[lane];
    #pragma unroll
    for (int c = 0; c < 64; ++c)
        acc = fmaf(sh[wv][c], Wn2[c * 64 + lane], acc);
    const float h2 = leaky(acc);

    // node layer 3 (64 -> 1)
    float p = h2 * Wn3[lane];
    #pragma unroll
    for (int off = 32; off > 0; off >>= 1)
        p += __shfl_xor(p, off, 64);
    if (lane == 0) {
        ws[row] = p + bn3[0];      // node_out
        out[row * 2 + 0] = x1;     // out0 = x[...,1]
    }
}

// ---------------- Kernel 2: pairwise coupling via MFMA ----------------
// One wave per (b,i). Tile = 16 j's. Lane (p=l&15, c4=(l>>4)*4):
//   b1[e]  = f16( leaky(pj[j][c4+e] + piu[i][c4+e]) )          (B-frag)
//   d1     = Wc2^T(hi) x b1 + (Wc2^T(lo) x b1 + bc2)           (2 MFMAs)
//   partial= sum_e leaky(d1[e]) * Wc3[c4+e]  (+ bc3 on group 0)
//   acc   += S[i][j] * partial
// Final butterfly over 64 lanes sums both the 4 channel groups and 16 pairs.
__global__ __launch_bounds__(64) void k2_pair_mfma(
    const float* __restrict__ Wc2, const float* __restrict__ bc2,
    const float* __restrict__ Wc3, const float* __restrict__ bc3,
    const float* __restrict__ ws, float* __restrict__ out)
{
    const int l  = threadIdx.x;       // 0..63
    const int p  = l & 15;            // pair slot within tile
    const int c4 = (l >> 4) << 2;     // channel base
    const int bi = blockIdx.x;        // b*512 + i
    const int b  = bi >> 9;
    const int i  = bi & 511;

    const float* node_out = ws;
    const float* pj  = ws + WS_PJ;
    const float* piu = ws + WS_PIU;
    const float* S   = ws + WS_S;

    // Wc2^T fragment, hi/lo split (weight quantization error ~2^-22)
    f16x4 w2hi, w2lo;
    f32x4 c1;                          // C for MFMA: bc2[c4+e]
    float w3[4];
    #pragma unroll
    for (int e = 0; e < 4; ++e) {
        const int c = c4 + e;
        const float w2 = Wc2[c * 16 + p];
        const _Float16 hw = (_Float16)w2;
        w2hi[e] = hw; w2lo[e] = (_Float16)(w2 - (float)hw);
        w3[e] = Wc3[c];
        c1[e] = bc2[c];
    }
    const float b3l = (l < 16) ? bc3[0] : 0.0f;   // bc3 once per pair (group 0)

    const f32x4 piuv = *reinterpret_cast<const f32x4*>(piu + bi * 16 + c4);
    const float* pjb = pj + b * 512 * 16;
    const float* Sr  = S + i * 512;

    float acc = 0.0f;
    #pragma unroll 2
    for (int t = 0; t < 32; ++t) {
        const int j = t * 16 + p;
        const f32x4 pjv = *reinterpret_cast<const f32x4*>(pjb + j * 16 + c4);

        f16x4 b1;
        #pragma unroll
        for (int e = 0; e < 4; ++e)
            b1[e] = (_Float16)leaky(pjv[e] + piuv[e]);

        f32x4 d1 = __builtin_amdgcn_mfma_f32_16x16x16f16(w2lo, b1, c1, 0, 0, 0);
        d1 = __builtin_amdgcn_mfma_f32_16x16x16f16(w2hi, b1, d1, 0, 0, 0);

        float partial = b3l;
        #pragma unroll
        for (int e = 0; e < 4; ++e)
            partial = fmaf(leaky(d1[e]), w3[e], partial);

        acc = fmaf(Sr[j], partial, acc);
    }

    // sum over 16 pairs x 4 channel groups
    #pragma unroll
    for (int off = 32; off > 0; off >>= 1)
        acc += __shfl_xor(acc, off, 64);

    if (l == 0)
        out[bi * 2 + 1] = node_out[bi] + acc;
}

extern "C" void kernel_launch(void* const* d_in, const int* in_sizes, int n_in,
                              void* d_out, int out_size, void* d_ws, size_t ws_size,
                              hipStream_t stream) {
    const float* x       = (const float*)d_in[0];
    const float* Wn1     = (const float*)d_in[1];
    const float* bn1     = (const float*)d_in[2];
    const float* Wn2     = (const float*)d_in[3];
    const float* bn2     = (const float*)d_in[4];
    const float* Wn3     = (const float*)d_in[5];
    const float* bn3     = (const float*)d_in[6];
    const float* Wc1     = (const float*)d_in[7];
    const float* bc1     = (const float*)d_in[8];
    const float* Wc2     = (const float*)d_in[9];
    const float* bc2     = (const float*)d_in[10];
    const float* Wc3     = (const float*)d_in[11];
    const float* bc3     = (const float*)d_in[12];
    const float* A_param = (const float*)d_in[13];
    float* out = (float*)d_out;
    float* ws  = (float*)d_ws;

    const int BN = 16 * 512;          // 8192 rows

    k1_fused<<<BN / 4, 256, 0, stream>>>(x, Wn1, bn1, Wn2, bn2, Wn3, bn3,
                                         Wc1, bc1, A_param, ws, out);
    k2_pair_mfma<<<BN, 64, 0, stream>>>(Wc2, bc2, Wc3, bc3, ws, out);
}